// Round 6
// baseline (654.539 us; speedup 1.0000x reference)
//
#include <hip/hip_runtime.h>

// SNN 2-layer forward: s2 = (( (x@W1.T >=1) @ W2.T) >= 1)
// B=4096, IN=3136, FEAT=6272, OUT=500; x and s1 binary {0,1}.
// Exact 3-limb i8-MFMA GEMM (w = d0*2^-7+d1*2^-14+d2*2^-21+r, |r|<=2^-22,
// i32 accumulation exact, f64 Horner exact) + worst-case-safe sparse fp64
// correction of all dots with |v_hat-1| <= K*2^-22.
//
// Round-6: occupancy + locality. Round-5's m=4 wave tile (192 AGPR + 128
// VGPR = 320 regs/wave) allowed only ~1 wave/SIMD -> intra-wave expand->MFMA
// serialization fully exposed (MfmaUtil 38%). Now: 512-thr blocks, 8 waves,
// wave m=2 (96 AGPR, ~166 regs/wave -> 3 waves/SIMD). Grid swizzled so
// consecutive blocks share the same B slice (bM on blockIdx.x) -> L2 reuse.
// A bits stay in VGPRs (expand16), B in LDS dbuf, one barrier per K-iter.

namespace {
constexpr int kB = 4096;
constexpr int kIn = 3136;        // 49 chunks of 64
constexpr int kFeat = 6272;      // 98 chunks of 64
constexpr int kFeatWords = 196;  // u32 per s1 row
constexpr int kOut = 500;
constexpr size_t kPlane1 = (size_t)kFeat * kIn;
constexpr size_t kW1F = 3 * kPlane1;                 // 59,006,976 (4802*12288)
constexpr size_t kW2F = (size_t)784 * 12288;         // 9,633,792
constexpr size_t kS1Bytes = (size_t)kB * kFeatWords * 4;  // 3,211,264 (x2)
constexpr size_t kXb2Bytes = (size_t)49 * kB * 8;    // 1,605,632
constexpr unsigned kCap1 = 2u << 20;
constexpr unsigned kCap2 = 1u << 16;
__device__ constexpr double kTau1 = 7.4769e-4;       // > 3136*2^-22
__device__ constexpr double kTau2 = 1.4955e-3;       // > 6272*2^-22
}  // namespace

typedef int v4i __attribute__((ext_vector_type(4)));
typedef int v16i __attribute__((ext_vector_type(16)));

__device__ __forceinline__ void gload_lds16(const void* g, void* l) {
  __builtin_amdgcn_global_load_lds((__attribute__((address_space(1))) void*)(g),
                                   (__attribute__((address_space(3))) void*)(l),
                                   16, 0, 0);
}

// 16 bits -> 16 i8 (byte i = bit i)
__device__ __forceinline__ v4i expand16(unsigned b) {
  unsigned u0 = (((b      ) & 0xFu) * 0x204081u) & 0x01010101u;
  unsigned u1 = (((b >> 4 ) & 0xFu) * 0x204081u) & 0x01010101u;
  unsigned u2 = (((b >> 8 ) & 0xFu) * 0x204081u) & 0x01010101u;
  unsigned u3 = (((b >> 12) & 0xFu) * 0x204081u) & 0x01010101u;
  return (v4i){(int)u0, (int)u1, (int)u2, (int)u3};
}

// exact 3-digit signed base-128 split; |w - sum| <= 2^-22
__device__ __forceinline__ void split3(float w, signed char* d) {
  float c = rintf(w * 128.f);
  d[0] = (signed char)(int)c;
  float r = fmaf(c, -7.8125e-03f, w);
  c = rintf(r * 16384.f);
  d[1] = (signed char)(int)c;
  r = fmaf(c, -6.103515625e-05f, r);
  c = rintf(r * 2097152.f);
  d[2] = (signed char)(int)c;
}

// ---------------------------------------------------------------------------
// W1 -> fragment-major limbs: slot(fb,kt,j,g) = 1KB of 64 feats x 16 k-bytes.
// ---------------------------------------------------------------------------
__global__ __launch_bounds__(256) void conv_w1F(const float* __restrict__ W,
                                                signed char* __restrict__ F) {
  const int bx = blockIdx.x;               // fb*49 + kt, < 4802
  const int fb = bx / 49;
  const int kt = bx % 49;
  const int f = threadIdx.x & 63;
  const int g = threadIdx.x >> 6;
  const float* src = W + (size_t)(fb * 64 + f) * kIn + kt * 64 + g * 16;
  union { signed char c[16]; int4 v; } o[3];
#pragma unroll
  for (int q = 0; q < 4; ++q) {
    const float4 w = *(const float4*)(src + q * 4);
    signed char d[4][3];
    split3(w.x, d[0]); split3(w.y, d[1]); split3(w.z, d[2]); split3(w.w, d[3]);
#pragma unroll
    for (int e = 0; e < 4; ++e)
#pragma unroll
      for (int j = 0; j < 3; ++j) o[j].c[q * 4 + e] = d[e][j];
  }
#pragma unroll
  for (int j = 0; j < 3; ++j)
    *(int4*)(F + ((size_t)bx * 3 + j) * 4096 + g * 1024 + f * 16) = o[j].v;
}

// W2 (padded to 512 rows) -> fragment-major limbs, slots (fb<8, kt<98, j, g)
__global__ __launch_bounds__(256) void conv_w2F(const float* __restrict__ W,
                                                signed char* __restrict__ F) {
  const int bx = blockIdx.x;               // fb*98 + kt, < 784
  const int fb = bx / 98;
  const int kt = bx % 98;
  const int f = threadIdx.x & 63;
  const int g = threadIdx.x >> 6;
  const int feat = fb * 64 + f;
  union { signed char c[16]; int4 v; } o[3];
#pragma unroll
  for (int q = 0; q < 4; ++q) {
    float4 w = {0.f, 0.f, 0.f, 0.f};
    if (feat < kOut)
      w = *(const float4*)(W + (size_t)feat * kFeat + kt * 64 + g * 16 + q * 4);
    signed char d[4][3];
    split3(w.x, d[0]); split3(w.y, d[1]); split3(w.z, d[2]); split3(w.w, d[3]);
#pragma unroll
    for (int e = 0; e < 4; ++e)
#pragma unroll
      for (int j = 0; j < 3; ++j) o[j].c[q * 4 + e] = d[e][j];
  }
#pragma unroll
  for (int j = 0; j < 3; ++j)
    *(int4*)(F + ((size_t)bx * 3 + j) * 4096 + g * 1024 + f * 16) = o[j].v;
}

// x -> transposed packed bits: xb2[kt*4096 + b]
__global__ __launch_bounds__(256) void pack_x2(const float* __restrict__ X,
                                               uint2* __restrict__ xb2) {
  const int wid = (blockIdx.x * 256 + threadIdx.x) >> 6;  // < 200,704
  const int lane = threadIdx.x & 63;
  const int b = wid / 49;
  const int g = wid % 49;
  const float v = X[(size_t)b * kIn + g * 64 + lane];
  const unsigned long long bal = __ballot(v != 0.f);
  if (lane == 0) xb2[(size_t)g * kB + b] = make_uint2((unsigned)bal, (unsigned)(bal >> 32));
}

// ---------------------------------------------------------------------------
// FC1: tile M=256,N=64,BK=64; 512 thr = 8 waves (4 waveM x 2 waveN);
// wave m=2 (64 rows), acc[2][3] v16i = 96 AGPR. Grid (16, 98): bM on x so
// consecutive blocks share the B slice (L2 reuse). One barrier per K-iter.
// ---------------------------------------------------------------------------
__global__ __launch_bounds__(512, 2) void fc1_v4(
    const uint2* __restrict__ xb2, const signed char* __restrict__ w1lF,
    unsigned* __restrict__ s1b, unsigned* __restrict__ s1T,
    unsigned* __restrict__ cnt, unsigned* __restrict__ list) {
  __shared__ __align__(16) signed char lds[24576];
  const int tid = threadIdx.x;
  const int lane = tid & 63;
  const int ln31 = lane & 31;
  const int half = lane >> 5;
  const int wv = tid >> 6;       // 0..7
  const int waveM = wv >> 1;     // 0..3
  const int waveN = wv & 1;      // 0..1
  const int bx = blockIdx.y;     // N-block (64 feats), 98 values
  const int bM = blockIdx.x * 256;

  // B staging: 12 slots/iter; wave wv stages slot wv, and wv+8 if wv<4
  const signed char* const gbase = w1lF + (size_t)bx * 49 * 12288;
  const bool has1 = (wv < 4);
  const unsigned sG0 = wv * 1024u + lane * 16u;
  const unsigned sL0 = wv * 1024u;
  const unsigned sG1 = (wv + 8) * 1024u + lane * 16u;
  const unsigned sL1 = (wv + 8) * 1024u;

  const uint2* const aptr = xb2 + bM + waveM * 64 + ln31;
  const unsigned bfeat = (waveN * 32 + ln31) * 16u;

  v16i acc[2][3] = {};
  uint2 abC[2], abN[2];
#pragma unroll
  for (int m = 0; m < 2; ++m) abC[m] = aptr[m * 32];
  gload_lds16(gbase + sG0, lds + sL0);
  if (has1) gload_lds16(gbase + sG1, lds + sL1);

  for (int kt = 0; kt < 49; ++kt) {
    __syncthreads();  // drains stage(kt); prev compute done
    const int cb = (kt & 1) * 12288;
    if (kt < 48) {
      const int nb = ((kt + 1) & 1) * 12288;
      const size_t go = (size_t)(kt + 1) * 12288;
      gload_lds16(gbase + go + sG0, lds + nb + sL0);
      if (has1) gload_lds16(gbase + go + sG1, lds + nb + sL1);
#pragma unroll
      for (int m = 0; m < 2; ++m) abN[m] = aptr[(size_t)(kt + 1) * kB + m * 32];
    }
#pragma unroll
    for (int kk = 0; kk < 2; ++kk) {
      const unsigned gsel = (kk * 2 + half) * 1024u;
      const v4i b0 = *(const v4i*)(lds + cb + 0 * 4096 + gsel + bfeat);
      const v4i b1 = *(const v4i*)(lds + cb + 1 * 4096 + gsel + bfeat);
      const v4i b2 = *(const v4i*)(lds + cb + 2 * 4096 + gsel + bfeat);
#pragma unroll
      for (int m = 0; m < 2; ++m) {
        const unsigned word = kk ? abC[m].y : abC[m].x;
        const v4i a = expand16((word >> (half * 16)) & 0xFFFFu);
        acc[m][0] = __builtin_amdgcn_mfma_i32_32x32x32_i8(a, b0, acc[m][0], 0, 0, 0);
        acc[m][1] = __builtin_amdgcn_mfma_i32_32x32x32_i8(a, b1, acc[m][1], 0, 0, 0);
        acc[m][2] = __builtin_amdgcn_mfma_i32_32x32x32_i8(a, b2, acc[m][2], 0, 0, 0);
      }
    }
    abC[0] = abN[0];
    abC[1] = abN[1];
  }

  const double s7 = 0.0078125;
  const int word = bx * 2 + waveN;
  const int fcol = word * 32 + ln31;
#pragma unroll
  for (int m = 0; m < 2; ++m) {
#pragma unroll
    for (int t = 0; t < 16; ++t) {
      double v = (double)acc[m][2][t];
      v = v * s7 + (double)acc[m][1][t];
      v = v * s7 + (double)acc[m][0][t];
      v = v * s7;
      const unsigned long long bal = __ballot(v >= 1.0);
      const int mrow = bM + waveM * 64 + m * 32 + (t & 3) + 8 * (t >> 2);
      if (lane == 0) {
        s1b[(size_t)mrow * kFeatWords + word] = (unsigned)bal;
        s1T[(size_t)word * kB + mrow] = (unsigned)bal;
      }
      if (lane == 32) {
        s1b[(size_t)(mrow + 4) * kFeatWords + word] = (unsigned)(bal >> 32);
        s1T[(size_t)word * kB + mrow + 4] = (unsigned)(bal >> 32);
      }
      if (fabs(v - 1.0) <= kTau1) {
        const unsigned idx = atomicAdd(cnt, 1u);
        if (idx < kCap1) list[idx] = ((unsigned)(mrow + 4 * half) << 13) | (unsigned)fcol;
      }
    }
  }
}

// exact fp64 recompute of flagged FC1 dots; fixes s1b AND s1T
__global__ __launch_bounds__(256) void fc1_correct(
    const float* __restrict__ x, const float* __restrict__ W1,
    const unsigned* __restrict__ cnt, const unsigned* __restrict__ list,
    unsigned* __restrict__ s1b, unsigned* __restrict__ s1T) {
  const unsigned n = min(cnt[0], kCap1);
  const int lane = threadIdx.x & 63;
  const int wid = (blockIdx.x * 256 + threadIdx.x) >> 6;
  const int nw = (gridDim.x * 256) >> 6;
  for (unsigned i = wid; i < n; i += nw) {
    const unsigned u = list[i];
    const int b = (int)(u >> 13);
    const int f = (int)(u & 8191u);
    double s = 0.0;
    for (int k = lane; k < kIn; k += 64)
      s = fma((double)x[(size_t)b * kIn + k], (double)W1[(size_t)f * kIn + k], s);
#pragma unroll
    for (int off = 32; off > 0; off >>= 1) s += __shfl_down(s, off);
    if (lane == 0) {
      const unsigned mask = 1u << (f & 31);
      unsigned* p1 = s1b + (size_t)b * kFeatWords + (f >> 5);
      unsigned* p2 = s1T + (size_t)(f >> 5) * kB + b;
      if (s >= 1.0) { atomicOr(p1, mask); atomicOr(p2, mask); }
      else          { atomicAnd(p1, ~mask); atomicAnd(p2, ~mask); }
    }
  }
}

// ---------------------------------------------------------------------------
// FC2: tile M=128,N=64,BK=64; 512 thr = 8 waves (4 waveM x 2 waveN);
// wave m=1 (32 rows), acc[3] = 48 AGPR. Grid (32, 8): bM on x. 98 iters.
// ---------------------------------------------------------------------------
__global__ __launch_bounds__(512, 2) void fc2_v4(
    const unsigned* __restrict__ s1T, const signed char* __restrict__ w2lF,
    float* __restrict__ out, unsigned* __restrict__ cnt,
    unsigned* __restrict__ list) {
  __shared__ __align__(16) signed char lds[24576];
  const int tid = threadIdx.x;
  const int lane = tid & 63;
  const int ln31 = lane & 31;
  const int half = lane >> 5;
  const int wv = tid >> 6;
  const int waveM = wv >> 1;     // 0..3
  const int waveN = wv & 1;      // 0..1
  const int bx = blockIdx.y;     // N-block (64 outs), 8 values
  const int bM = blockIdx.x * 128;

  const signed char* const gbase = w2lF + (size_t)bx * 98 * 12288;
  const bool has1 = (wv < 4);
  const unsigned sG0 = wv * 1024u + lane * 16u;
  const unsigned sL0 = wv * 1024u;
  const unsigned sG1 = (wv + 8) * 1024u + lane * 16u;
  const unsigned sL1 = (wv + 8) * 1024u;

  const unsigned* const aptr = s1T + bM + waveM * 32 + ln31;
  const unsigned bfeat = (waveN * 32 + ln31) * 16u;

  v16i acc[3] = {};
  unsigned abC[2], abN[2];
#pragma unroll
  for (int kk = 0; kk < 2; ++kk) abC[kk] = aptr[(size_t)kk * kB];
  gload_lds16(gbase + sG0, lds + sL0);
  if (has1) gload_lds16(gbase + sG1, lds + sL1);

  for (int kt = 0; kt < 98; ++kt) {
    __syncthreads();
    const int cb = (kt & 1) * 12288;
    if (kt < 97) {
      const int nb = ((kt + 1) & 1) * 12288;
      const size_t go = (size_t)(kt + 1) * 12288;
      gload_lds16(gbase + go + sG0, lds + nb + sL0);
      if (has1) gload_lds16(gbase + go + sG1, lds + nb + sL1);
#pragma unroll
      for (int kk = 0; kk < 2; ++kk)
        abN[kk] = aptr[((size_t)(kt + 1) * 2 + kk) * kB];
    }
#pragma unroll
    for (int kk = 0; kk < 2; ++kk) {
      const unsigned gsel = (kk * 2 + half) * 1024u;
      const v4i b0 = *(const v4i*)(lds + cb + 0 * 4096 + gsel + bfeat);
      const v4i b1 = *(const v4i*)(lds + cb + 1 * 4096 + gsel + bfeat);
      const v4i b2 = *(const v4i*)(lds + cb + 2 * 4096 + gsel + bfeat);
      const v4i a = expand16((abC[kk] >> (half * 16)) & 0xFFFFu);
      acc[0] = __builtin_amdgcn_mfma_i32_32x32x32_i8(a, b0, acc[0], 0, 0, 0);
      acc[1] = __builtin_amdgcn_mfma_i32_32x32x32_i8(a, b1, acc[1], 0, 0, 0);
      acc[2] = __builtin_amdgcn_mfma_i32_32x32x32_i8(a, b2, acc[2], 0, 0, 0);
    }
    abC[0] = abN[0];
    abC[1] = abN[1];
  }

  const double s7 = 0.0078125;
  const int o = bx * 64 + waveN * 32 + ln31;
#pragma unroll
  for (int t = 0; t < 16; ++t) {
    double v = (double)acc[2][t];
    v = v * s7 + (double)acc[1][t];
    v = v * s7 + (double)acc[0][t];
    v = v * s7;
    const int b = bM + waveM * 32 + (t & 3) + 8 * (t >> 2) + 4 * half;
    if (o < kOut) {
      out[(size_t)b * kOut + o] = (v >= 1.0) ? 1.0f : 0.0f;
      if (fabs(v - 1.0) <= kTau2) {
        const unsigned idx = atomicAdd(cnt, 1u);
        if (idx < kCap2) list[idx] = ((unsigned)b << 13) | (unsigned)o;
      }
    }
  }
}

// exact fp64 recompute of flagged FC2 dots (reads row-major s1b)
__global__ __launch_bounds__(256) void fc2_correct(
    const unsigned* __restrict__ s1b, const float* __restrict__ W2,
    const unsigned* __restrict__ cnt, const unsigned* __restrict__ list,
    float* __restrict__ out) {
  const unsigned n = min(cnt[0], kCap2);
  const int lane = threadIdx.x & 63;
  const int wid = (blockIdx.x * 256 + threadIdx.x) >> 6;
  const int nw = (gridDim.x * 256) >> 6;
  for (unsigned i = wid; i < n; i += nw) {
    const unsigned u = list[i];
    const int b = (int)(u >> 13);
    const int o = (int)(u & 8191u);
    double s = 0.0;
    for (int k = lane; k < kFeat; k += 64) {
      const unsigned w = s1b[(size_t)b * kFeatWords + (k >> 5)];
      if ((w >> (k & 31)) & 1u) s += (double)W2[(size_t)o * kFeat + k];
    }
#pragma unroll
    for (int off = 32; off > 0; off >>= 1) s += __shfl_down(s, off);
    if (lane == 0) out[(size_t)b * kOut + o] = (s >= 1.0) ? 1.0f : 0.0f;
  }
}

// ---------------------------------------------------------------------------
// fp64 fallback (round-1 validated) — only if ws too small.
// ---------------------------------------------------------------------------
__global__ __launch_bounds__(256) void snn_fc1(const float* __restrict__ x,
                                               const float* __restrict__ W1,
                                               unsigned int* __restrict__ s1bits) {
  __shared__ double Xd[32][66];
  __shared__ double Wd[32][66];
  __shared__ unsigned int spikes[64][2];
  const int tid = threadIdx.x;
  const int tx = tid & 15;
  const int ty = tid >> 4;
  const int b0 = blockIdx.y * 64;
  const int f0 = blockIdx.x * 64;
  if (tid < 128) spikes[tid >> 1][tid & 1] = 0u;
  double acc[4][4];
#pragma unroll
  for (int j = 0; j < 4; ++j)
#pragma unroll
    for (int i = 0; i < 4; ++i) acc[j][i] = 0.0;
  const int rl = tid >> 2;
  const int kq = (tid & 3) * 8;
  const float* xrow = x + (size_t)(b0 + rl) * kIn + kq;
  const float* wrow = W1 + (size_t)(f0 + rl) * kIn + kq;
  for (int kc = 0; kc < kIn; kc += 32) {
    const float4 xv0 = *(const float4*)(xrow + kc);
    const float4 xv1 = *(const float4*)(xrow + kc + 4);
    const float4 wv0 = *(const float4*)(wrow + kc);
    const float4 wv1 = *(const float4*)(wrow + kc + 4);
    __syncthreads();
    Xd[kq + 0][rl] = (double)xv0.x; Xd[kq + 1][rl] = (double)xv0.y;
    Xd[kq + 2][rl] = (double)xv0.z; Xd[kq + 3][rl] = (double)xv0.w;
    Xd[kq + 4][rl] = (double)xv1.x; Xd[kq + 5][rl] = (double)xv1.y;
    Xd[kq + 6][rl] = (double)xv1.z; Xd[kq + 7][rl] = (double)xv1.w;
    Wd[kq + 0][rl] = (double)wv0.x; Wd[kq + 1][rl] = (double)wv0.y;
    Wd[kq + 2][rl] = (double)wv0.z; Wd[kq + 3][rl] = (double)wv0.w;
    Wd[kq + 4][rl] = (double)wv1.x; Wd[kq + 5][rl] = (double)wv1.y;
    Wd[kq + 6][rl] = (double)wv1.z; Wd[kq + 7][rl] = (double)wv1.w;
    __syncthreads();
#pragma unroll
    for (int k = 0; k < 32; ++k) {
      const double2 xa = *(const double2*)&Xd[k][ty * 4];
      const double2 xb = *(const double2*)&Xd[k][ty * 4 + 2];
      const double2 wa = *(const double2*)&Wd[k][tx * 4];
      const double2 wb = *(const double2*)&Wd[k][tx * 4 + 2];
      const double xv[4] = {xa.x, xa.y, xb.x, xb.y};
      const double wv[4] = {wa.x, wa.y, wb.x, wb.y};
#pragma unroll
      for (int j = 0; j < 4; ++j)
#pragma unroll
        for (int i = 0; i < 4; ++i) acc[j][i] += xv[j] * wv[i];
    }
  }
  __syncthreads();
#pragma unroll
  for (int j = 0; j < 4; ++j) {
    unsigned int nib = 0u;
#pragma unroll
    for (int i = 0; i < 4; ++i) nib |= (acc[j][i] >= 1.0 ? 1u : 0u) << i;
    atomicOr(&spikes[ty * 4 + j][tx >> 3], nib << ((tx * 4) & 31));
  }
  __syncthreads();
  if (tid < 128) {
    const int r = tid >> 1;
    const int w = tid & 1;
    s1bits[(size_t)(b0 + r) * kFeatWords + (f0 >> 5) + w] = spikes[r][w];
  }
}

__global__ __launch_bounds__(256) void snn_fc2(const unsigned int* __restrict__ s1bits,
                                               const float* __restrict__ W2,
                                               float* __restrict__ out) {
  __shared__ double Wd[32][66];
  __shared__ unsigned int Sb[64];
  const int tid = threadIdx.x;
  const int tx = tid & 15;
  const int ty = tid >> 4;
  const int b0 = blockIdx.y * 64;
  const int o0 = blockIdx.x * 64;
  double acc[4][4];
#pragma unroll
  for (int j = 0; j < 4; ++j)
#pragma unroll
    for (int i = 0; i < 4; ++i) acc[j][i] = 0.0;
  const int rl = tid >> 2;
  const int kq = (tid & 3) * 8;
  int orow = o0 + rl;
  if (orow >= kOut) orow = kOut - 1;
  const float* wrow = W2 + (size_t)orow * kFeat + kq;
  for (int kc = 0; kc < kFeat; kc += 32) {
    const float4 wv0 = *(const float4*)(wrow + kc);
    const float4 wv1 = *(const float4*)(wrow + kc + 4);
    unsigned int sword = 0u;
    if (tid < 64) sword = s1bits[(size_t)(b0 + tid) * kFeatWords + (kc >> 5)];
    __syncthreads();
    Wd[kq + 0][rl] = (double)wv0.x; Wd[kq + 1][rl] = (double)wv0.y;
    Wd[kq + 2][rl] = (double)wv0.z; Wd[kq + 3][rl] = (double)wv0.w;
    Wd[kq + 4][rl] = (double)wv1.x; Wd[kq + 5][rl] = (double)wv1.y;
    Wd[kq + 6][rl] = (double)wv1.z; Wd[kq + 7][rl] = (double)wv1.w;
    if (tid < 64) Sb[tid] = sword;
    __syncthreads();
    const unsigned int rw0 = Sb[ty * 4 + 0];
    const unsigned int rw1 = Sb[ty * 4 + 1];
    const unsigned int rw2 = Sb[ty * 4 + 2];
    const unsigned int rw3 = Sb[ty * 4 + 3];
#pragma unroll
    for (int k = 0; k < 32; ++k) {
      const double2 wa = *(const double2*)&Wd[k][tx * 4];
      const double2 wb = *(const double2*)&Wd[k][tx * 4 + 2];
      const double wv[4] = {wa.x, wa.y, wb.x, wb.y};
      const double sv[4] = {(double)((rw0 >> k) & 1u), (double)((rw1 >> k) & 1u),
                            (double)((rw2 >> k) & 1u), (double)((rw3 >> k) & 1u)};
#pragma unroll
      for (int j = 0; j < 4; ++j)
#pragma unroll
        for (int i = 0; i < 4; ++i) acc[j][i] += sv[j] * wv[i];
    }
  }
#pragma unroll
  for (int j = 0; j < 4; ++j) {
    const int b = b0 + ty * 4 + j;
#pragma unroll
    for (int i = 0; i < 4; ++i) {
      const int o = o0 + tx * 4 + i;
      if (o < kOut) out[(size_t)b * kOut + o] = (acc[j][i] >= 1.0) ? 1.0f : 0.0f;
    }
  }
}

extern "C" void kernel_launch(void* const* d_in, const int* in_sizes, int n_in,
                              void* d_out, int out_size, void* d_ws, size_t ws_size,
                              hipStream_t stream) {
  const float* x = (const float*)d_in[0];
  const float* W1 = (const float*)d_in[1];
  const float* W2 = (const float*)d_in[2];
  float* out = (float*)d_out;

  char* p = (char*)d_ws;
  signed char* w1lF = (signed char*)p;   p += kW1F;
  signed char* w2lF = (signed char*)p;   p += kW2F;
  unsigned* s1b = (unsigned*)p;          p += kS1Bytes;
  unsigned* s1T = (unsigned*)p;          p += kS1Bytes;
  uint2* xb2 = (uint2*)p;                p += kXb2Bytes;
  unsigned* list1 = (unsigned*)p;        p += (size_t)kCap1 * 4;
  unsigned* list2 = (unsigned*)p;        p += (size_t)kCap2 * 4;
  unsigned* ctrs = (unsigned*)p;         p += 256;
  const size_t need = (size_t)(p - (char*)d_ws);  // ~85 MB

  if (ws_size >= need) {
    hipMemsetAsync(ctrs, 0, 32, stream);  // ctrs[0]=fc1 cnt, ctrs[4]=fc2 cnt
    conv_w1F<<<4802, 256, 0, stream>>>(W1, w1lF);
    conv_w2F<<<784, 256, 0, stream>>>(W2, w2lF);
    pack_x2<<<50176, 256, 0, stream>>>(x, xb2);
    fc1_v4<<<dim3(16, 98), 512, 0, stream>>>(xb2, w1lF, s1b, s1T, ctrs, list1);
    fc1_correct<<<1024, 256, 0, stream>>>(x, W1, ctrs, list1, s1b, s1T);
    fc2_v4<<<dim3(32, 8), 512, 0, stream>>>(s1T, w2lF, out, ctrs + 4, list2);
    fc2_correct<<<64, 256, 0, stream>>>(s1b, W2, ctrs + 4, list2, out);
  } else {
    unsigned* s1 = (unsigned*)d_ws;
    snn_fc1<<<dim3(98, 64), 256, 0, stream>>>(x, W1, s1);
    snn_fc2<<<dim3(8, 64), 256, 0, stream>>>(s1, W2, out);
  }
}

// Round 7
// 630.194 us; speedup vs baseline: 1.0386x; 1.0386x over previous
//
#include <hip/hip_runtime.h>

// SNN 2-layer forward: s2 = (( (x@W1.T >=1) @ W2.T) >= 1)
// B=4096, IN=3136, FEAT=6272, OUT=500; x and s1 binary {0,1}.
// Exact 3-limb i8-MFMA GEMM (w = d0*2^-7+d1*2^-14+d2*2^-21+r, |r|<=2^-22,
// i32 MFMA accumulation exact, f64 Horner exact) + worst-case-safe sparse
// fp64 correction of all dots with |v_hat-1| <= K*2^-22.
//
// Round-7: NO LDS, NO BARRIER. R5/R6 showed the per-iter __syncthreads +
// vmcnt(0) drain at <=2 waves/SIMD pays ~2400 stall cyc/iter (90% idle,
// HBM 9%). B is fragment-contiguous in w1lF/w2lF, so waves load their
// three 16B B-frags straight to VGPRs (coalesced 1KB dwordx4, L2-broadcast
// across waves sharing the slice), register-double-buffered, unrolled x2.
// Wave tile 32x32 (acc[3]=48 AGPR, ~123 regs total) + launch_bounds(256,4)
// -> 4 waves/SIMD from 4 independent blocks/CU; compiler emits fine-grained
// vmcnt(N), latency hidden by TLP instead of a barrier pipeline.

namespace {
constexpr int kB = 4096;
constexpr int kIn = 3136;        // 49 chunks of 64
constexpr int kFeat = 6272;      // 98 chunks of 64
constexpr int kFeatWords = 196;  // u32 per s1 row
constexpr int kOut = 500;
constexpr size_t kPlane1 = (size_t)kFeat * kIn;
constexpr size_t kW1F = 3 * kPlane1;                 // 59,006,976 (4802*12288)
constexpr size_t kW2F = (size_t)784 * 12288;         // 9,633,792
constexpr size_t kS1Bytes = (size_t)kB * kFeatWords * 4;  // 3,211,264 (x2)
constexpr size_t kXb2Bytes = (size_t)49 * kB * 8;    // 1,605,632
constexpr unsigned kCap1 = 2u << 20;
constexpr unsigned kCap2 = 1u << 16;
__device__ constexpr double kTau1 = 7.4769e-4;       // > 3136*2^-22
__device__ constexpr double kTau2 = 1.4955e-3;       // > 6272*2^-22
}  // namespace

typedef int v4i __attribute__((ext_vector_type(4)));
typedef int v16i __attribute__((ext_vector_type(16)));

// 16 bits -> 16 i8 (byte i = bit i)
__device__ __forceinline__ v4i expand16(unsigned b) {
  unsigned u0 = (((b      ) & 0xFu) * 0x204081u) & 0x01010101u;
  unsigned u1 = (((b >> 4 ) & 0xFu) * 0x204081u) & 0x01010101u;
  unsigned u2 = (((b >> 8 ) & 0xFu) * 0x204081u) & 0x01010101u;
  unsigned u3 = (((b >> 12) & 0xFu) * 0x204081u) & 0x01010101u;
  return (v4i){(int)u0, (int)u1, (int)u2, (int)u3};
}

// exact 3-digit signed base-128 split; |w - sum| <= 2^-22
__device__ __forceinline__ void split3(float w, signed char* d) {
  float c = rintf(w * 128.f);
  d[0] = (signed char)(int)c;
  float r = fmaf(c, -7.8125e-03f, w);
  c = rintf(r * 16384.f);
  d[1] = (signed char)(int)c;
  r = fmaf(c, -6.103515625e-05f, r);
  c = rintf(r * 2097152.f);
  d[2] = (signed char)(int)c;
}

// ---------------------------------------------------------------------------
// W1 -> fragment-major limbs: slot(fb,kt,j,g) = 1KB of 64 feats x 16 k-bytes.
// addr = ((fb*49+kt)*3 + j)*4096 + g*1024 + f*16 + i ; k = kt*64+g*16+i.
// ---------------------------------------------------------------------------
__global__ __launch_bounds__(256) void conv_w1F(const float* __restrict__ W,
                                                signed char* __restrict__ F) {
  const int bx = blockIdx.x;               // fb*49 + kt, < 4802
  const int fb = bx / 49;
  const int kt = bx % 49;
  const int f = threadIdx.x & 63;
  const int g = threadIdx.x >> 6;
  const float* src = W + (size_t)(fb * 64 + f) * kIn + kt * 64 + g * 16;
  union { signed char c[16]; int4 v; } o[3];
#pragma unroll
  for (int q = 0; q < 4; ++q) {
    const float4 w = *(const float4*)(src + q * 4);
    signed char d[4][3];
    split3(w.x, d[0]); split3(w.y, d[1]); split3(w.z, d[2]); split3(w.w, d[3]);
#pragma unroll
    for (int e = 0; e < 4; ++e)
#pragma unroll
      for (int j = 0; j < 3; ++j) o[j].c[q * 4 + e] = d[e][j];
  }
#pragma unroll
  for (int j = 0; j < 3; ++j)
    *(int4*)(F + ((size_t)bx * 3 + j) * 4096 + g * 1024 + f * 16) = o[j].v;
}

// W2 (padded to 512 rows) -> fragment-major limbs, slots (fb<8, kt<98, j, g)
__global__ __launch_bounds__(256) void conv_w2F(const float* __restrict__ W,
                                                signed char* __restrict__ F) {
  const int bx = blockIdx.x;               // fb*98 + kt, < 784
  const int fb = bx / 98;
  const int kt = bx % 98;
  const int f = threadIdx.x & 63;
  const int g = threadIdx.x >> 6;
  const int feat = fb * 64 + f;
  union { signed char c[16]; int4 v; } o[3];
#pragma unroll
  for (int q = 0; q < 4; ++q) {
    float4 w = {0.f, 0.f, 0.f, 0.f};
    if (feat < kOut)
      w = *(const float4*)(W + (size_t)feat * kFeat + kt * 64 + g * 16 + q * 4);
    signed char d[4][3];
    split3(w.x, d[0]); split3(w.y, d[1]); split3(w.z, d[2]); split3(w.w, d[3]);
#pragma unroll
    for (int e = 0; e < 4; ++e)
#pragma unroll
      for (int j = 0; j < 3; ++j) o[j].c[q * 4 + e] = d[e][j];
  }
#pragma unroll
  for (int j = 0; j < 3; ++j)
    *(int4*)(F + ((size_t)bx * 3 + j) * 4096 + g * 1024 + f * 16) = o[j].v;
}

// x -> transposed packed bits: xb2[kt*4096 + b]
__global__ __launch_bounds__(256) void pack_x2(const float* __restrict__ X,
                                               uint2* __restrict__ xb2) {
  const int wid = (blockIdx.x * 256 + threadIdx.x) >> 6;  // < 200,704
  const int lane = threadIdx.x & 63;
  const int b = wid / 49;
  const int g = wid % 49;
  const float v = X[(size_t)b * kIn + g * 64 + lane];
  const unsigned long long bal = __ballot(v != 0.f);
  if (lane == 0) xb2[(size_t)g * kB + b] = make_uint2((unsigned)bal, (unsigned)(bal >> 32));
}

// ---------------------------------------------------------------------------
// FC1 v5: no LDS/no barrier. 256 thr = 4 waves (2 waveM x 2 waveN), wave
// tile 32x32, acc[3] (48 AGPR). B frags dwordx4 from global (L2), register
// double-buffered, unroll x2. Grid (64, 98), bM on x (L2/XCD locality).
// ---------------------------------------------------------------------------
__global__ __launch_bounds__(256, 4) void fc1_v5(
    const uint2* __restrict__ xb2, const signed char* __restrict__ w1lF,
    unsigned* __restrict__ s1b, unsigned* __restrict__ s1T,
    unsigned* __restrict__ cnt, unsigned* __restrict__ list) {
  const int tid = threadIdx.x;
  const int lane = tid & 63;
  const int ln31 = lane & 31;
  const int half = lane >> 5;
  const int wv = tid >> 6;
  const int waveM = wv >> 1;   // 0..1
  const int waveN = wv & 1;    // 0..1
  const int bx = blockIdx.y;   // N-block (64 feats)
  const int bM = blockIdx.x * 64;

  const int row = bM + waveM * 32 + ln31;
  const uint2* const aptr = xb2 + row;
  const int fl = waveN * 32 + ln31;
  const signed char* const bbase =
      w1lF + (size_t)(bx * 49) * 12288 + half * 1024u + fl * 16u;

  v16i acc[3] = {};
  v4i b0[6], b1[6];
  uint2 a0, a1;

#define LOAD_TILE(nk, bf, ab)                                   \
  {                                                             \
    const signed char* bp = bbase + (size_t)(nk) * 12288;       \
    bf[0] = *(const v4i*)(bp);                                  \
    bf[1] = *(const v4i*)(bp + 2048);                           \
    bf[2] = *(const v4i*)(bp + 4096);                           \
    bf[3] = *(const v4i*)(bp + 6144);                           \
    bf[4] = *(const v4i*)(bp + 8192);                           \
    bf[5] = *(const v4i*)(bp + 10240);                          \
    ab = aptr[(size_t)(nk) * kB];                               \
  }
#define COMPUTE_TILE(bf, ab)                                                    \
  {                                                                             \
    _Pragma("unroll")                                                           \
    for (int kk = 0; kk < 2; ++kk) {                                            \
      const unsigned word = kk ? (ab).y : (ab).x;                               \
      const v4i a = expand16((word >> (half * 16)) & 0xFFFFu);                  \
      acc[0] = __builtin_amdgcn_mfma_i32_32x32x32_i8(a, bf[kk], acc[0], 0,0,0); \
      acc[1] = __builtin_amdgcn_mfma_i32_32x32x32_i8(a, bf[2+kk], acc[1],0,0,0);\
      acc[2] = __builtin_amdgcn_mfma_i32_32x32x32_i8(a, bf[4+kk], acc[2],0,0,0);\
    }                                                                           \
  }

  LOAD_TILE(0, b0, a0);
  for (int kt = 0; kt + 2 <= 49; kt += 2) {
    LOAD_TILE(kt + 1, b1, a1);
    COMPUTE_TILE(b0, a0);
    const int nk2 = (kt + 2 < 49) ? kt + 2 : 48;
    LOAD_TILE(nk2, b0, a0);
    COMPUTE_TILE(b1, a1);
  }
  COMPUTE_TILE(b0, a0);  // kt = 48 (49 is odd)

  const double s7 = 0.0078125;
  const int word = bx * 2 + waveN;
  const int fcol = word * 32 + ln31;
#pragma unroll
  for (int t = 0; t < 16; ++t) {
    double v = (double)acc[2][t];
    v = v * s7 + (double)acc[1][t];
    v = v * s7 + (double)acc[0][t];
    v = v * s7;
    const unsigned long long bal = __ballot(v >= 1.0);
    const int mrow = bM + waveM * 32 + (t & 3) + 8 * (t >> 2);
    if (lane == 0) {
      s1b[(size_t)mrow * kFeatWords + word] = (unsigned)bal;
      s1T[(size_t)word * kB + mrow] = (unsigned)bal;
    }
    if (lane == 32) {
      s1b[(size_t)(mrow + 4) * kFeatWords + word] = (unsigned)(bal >> 32);
      s1T[(size_t)word * kB + mrow + 4] = (unsigned)(bal >> 32);
    }
    if (fabs(v - 1.0) <= kTau1) {
      const unsigned idx = atomicAdd(cnt, 1u);
      if (idx < kCap1) list[idx] = ((unsigned)(mrow + 4 * half) << 13) | (unsigned)fcol;
    }
  }
#undef LOAD_TILE
#undef COMPUTE_TILE
}

// exact fp64 recompute of flagged FC1 dots; fixes s1b AND s1T
__global__ __launch_bounds__(256) void fc1_correct(
    const float* __restrict__ x, const float* __restrict__ W1,
    const unsigned* __restrict__ cnt, const unsigned* __restrict__ list,
    unsigned* __restrict__ s1b, unsigned* __restrict__ s1T) {
  const unsigned n = min(cnt[0], kCap1);
  const int lane = threadIdx.x & 63;
  const int wid = (blockIdx.x * 256 + threadIdx.x) >> 6;
  const int nw = (gridDim.x * 256) >> 6;
  for (unsigned i = wid; i < n; i += nw) {
    const unsigned u = list[i];
    const int b = (int)(u >> 13);
    const int f = (int)(u & 8191u);
    double s = 0.0;
    for (int k = lane; k < kIn; k += 64)
      s = fma((double)x[(size_t)b * kIn + k], (double)W1[(size_t)f * kIn + k], s);
#pragma unroll
    for (int off = 32; off > 0; off >>= 1) s += __shfl_down(s, off);
    if (lane == 0) {
      const unsigned mask = 1u << (f & 31);
      unsigned* p1 = s1b + (size_t)b * kFeatWords + (f >> 5);
      unsigned* p2 = s1T + (size_t)(f >> 5) * kB + b;
      if (s >= 1.0) { atomicOr(p1, mask); atomicOr(p2, mask); }
      else          { atomicAnd(p1, ~mask); atomicAnd(p2, ~mask); }
    }
  }
}

// ---------------------------------------------------------------------------
// FC2 v5: same barrier-free structure. Wave 32x32, acc[3]. A bits from s1T
// (two dword loads per tile). Grid (64, 8), 98 K-tiles (even -> no tail).
// ---------------------------------------------------------------------------
__global__ __launch_bounds__(256, 4) void fc2_v5(
    const unsigned* __restrict__ s1T, const signed char* __restrict__ w2lF,
    float* __restrict__ out, unsigned* __restrict__ cnt,
    unsigned* __restrict__ list) {
  const int tid = threadIdx.x;
  const int lane = tid & 63;
  const int ln31 = lane & 31;
  const int half = lane >> 5;
  const int wv = tid >> 6;
  const int waveM = wv >> 1;   // 0..1
  const int waveN = wv & 1;    // 0..1
  const int bx = blockIdx.y;   // N-block (64 outs)
  const int bM = blockIdx.x * 64;

  const int row = bM + waveM * 32 + ln31;
  const unsigned* const aptr = s1T + row;
  const int fl = waveN * 32 + ln31;
  const signed char* const bbase =
      w2lF + (size_t)(bx * 98) * 12288 + half * 1024u + fl * 16u;

  v16i acc[3] = {};
  v4i b0[6], b1[6];
  uint2 a0, a1;

#define LOAD_TILE(nk, bf, ab)                                   \
  {                                                             \
    const signed char* bp = bbase + (size_t)(nk) * 12288;       \
    bf[0] = *(const v4i*)(bp);                                  \
    bf[1] = *(const v4i*)(bp + 2048);                           \
    bf[2] = *(const v4i*)(bp + 4096);                           \
    bf[3] = *(const v4i*)(bp + 6144);                           \
    bf[4] = *(const v4i*)(bp + 8192);                           \
    bf[5] = *(const v4i*)(bp + 10240);                          \
    (ab).x = aptr[(size_t)((nk) * 2) * kB];                     \
    (ab).y = aptr[(size_t)((nk) * 2 + 1) * kB];                 \
  }
#define COMPUTE_TILE(bf, ab)                                                    \
  {                                                                             \
    _Pragma("unroll")                                                           \
    for (int kk = 0; kk < 2; ++kk) {                                            \
      const unsigned word = kk ? (ab).y : (ab).x;                               \
      const v4i a = expand16((word >> (half * 16)) & 0xFFFFu);                  \
      acc[0] = __builtin_amdgcn_mfma_i32_32x32x32_i8(a, bf[kk], acc[0], 0,0,0); \
      acc[1] = __builtin_amdgcn_mfma_i32_32x32x32_i8(a, bf[2+kk], acc[1],0,0,0);\
      acc[2] = __builtin_amdgcn_mfma_i32_32x32x32_i8(a, bf[4+kk], acc[2],0,0,0);\
    }                                                                           \
  }

  LOAD_TILE(0, b0, a0);
  for (int kt = 0; kt + 2 <= 98; kt += 2) {
    LOAD_TILE(kt + 1, b1, a1);
    COMPUTE_TILE(b0, a0);
    const int nk2 = (kt + 2 < 98) ? kt + 2 : 97;  // last reload harmless
    LOAD_TILE(nk2, b0, a0);
    COMPUTE_TILE(b1, a1);
  }
  // 98 even: all tiles consumed in the loop.

  const double s7 = 0.0078125;
  const int o = bx * 64 + waveN * 32 + ln31;
#pragma unroll
  for (int t = 0; t < 16; ++t) {
    double v = (double)acc[2][t];
    v = v * s7 + (double)acc[1][t];
    v = v * s7 + (double)acc[0][t];
    v = v * s7;
    const int b = bM + waveM * 32 + (t & 3) + 8 * (t >> 2) + 4 * half;
    if (o < kOut) {
      out[(size_t)b * kOut + o] = (v >= 1.0) ? 1.0f : 0.0f;
      if (fabs(v - 1.0) <= kTau2) {
        const unsigned idx = atomicAdd(cnt, 1u);
        if (idx < kCap2) list[idx] = ((unsigned)b << 13) | (unsigned)o;
      }
    }
  }
#undef LOAD_TILE
#undef COMPUTE_TILE
}

// exact fp64 recompute of flagged FC2 dots (reads row-major s1b)
__global__ __launch_bounds__(256) void fc2_correct(
    const unsigned* __restrict__ s1b, const float* __restrict__ W2,
    const unsigned* __restrict__ cnt, const unsigned* __restrict__ list,
    float* __restrict__ out) {
  const unsigned n = min(cnt[0], kCap2);
  const int lane = threadIdx.x & 63;
  const int wid = (blockIdx.x * 256 + threadIdx.x) >> 6;
  const int nw = (gridDim.x * 256) >> 6;
  for (unsigned i = wid; i < n; i += nw) {
    const unsigned u = list[i];
    const int b = (int)(u >> 13);
    const int o = (int)(u & 8191u);
    double s = 0.0;
    for (int k = lane; k < kFeat; k += 64) {
      const unsigned w = s1b[(size_t)b * kFeatWords + (k >> 5)];
      if ((w >> (k & 31)) & 1u) s += (double)W2[(size_t)o * kFeat + k];
    }
#pragma unroll
    for (int off = 32; off > 0; off >>= 1) s += __shfl_down(s, off);
    if (lane == 0) out[(size_t)b * kOut + o] = (s >= 1.0) ? 1.0f : 0.0f;
  }
}

// ---------------------------------------------------------------------------
// fp64 fallback (round-1 validated) — only if ws too small.
// ---------------------------------------------------------------------------
__global__ __launch_bounds__(256) void snn_fc1(const float* __restrict__ x,
                                               const float* __restrict__ W1,
                                               unsigned int* __restrict__ s1bits) {
  __shared__ double Xd[32][66];
  __shared__ double Wd[32][66];
  __shared__ unsigned int spikes[64][2];
  const int tid = threadIdx.x;
  const int tx = tid & 15;
  const int ty = tid >> 4;
  const int b0 = blockIdx.y * 64;
  const int f0 = blockIdx.x * 64;
  if (tid < 128) spikes[tid >> 1][tid & 1] = 0u;
  double acc[4][4];
#pragma unroll
  for (int j = 0; j < 4; ++j)
#pragma unroll
    for (int i = 0; i < 4; ++i) acc[j][i] = 0.0;
  const int rl = tid >> 2;
  const int kq = (tid & 3) * 8;
  const float* xrow = x + (size_t)(b0 + rl) * kIn + kq;
  const float* wrow = W1 + (size_t)(f0 + rl) * kIn + kq;
  for (int kc = 0; kc < kIn; kc += 32) {
    const float4 xv0 = *(const float4*)(xrow + kc);
    const float4 xv1 = *(const float4*)(xrow + kc + 4);
    const float4 wv0 = *(const float4*)(wrow + kc);
    const float4 wv1 = *(const float4*)(wrow + kc + 4);
    __syncthreads();
    Xd[kq + 0][rl] = (double)xv0.x; Xd[kq + 1][rl] = (double)xv0.y;
    Xd[kq + 2][rl] = (double)xv0.z; Xd[kq + 3][rl] = (double)xv0.w;
    Xd[kq + 4][rl] = (double)xv1.x; Xd[kq + 5][rl] = (double)xv1.y;
    Xd[kq + 6][rl] = (double)xv1.z; Xd[kq + 7][rl] = (double)xv1.w;
    Wd[kq + 0][rl] = (double)wv0.x; Wd[kq + 1][rl] = (double)wv0.y;
    Wd[kq + 2][rl] = (double)wv0.z; Wd[kq + 3][rl] = (double)wv0.w;
    Wd[kq + 4][rl] = (double)wv1.x; Wd[kq + 5][rl] = (double)wv1.y;
    Wd[kq + 6][rl] = (double)wv1.z; Wd[kq + 7][rl] = (double)wv1.w;
    __syncthreads();
#pragma unroll
    for (int k = 0; k < 32; ++k) {
      const double2 xa = *(const double2*)&Xd[k][ty * 4];
      const double2 xb = *(const double2*)&Xd[k][ty * 4 + 2];
      const double2 wa = *(const double2*)&Wd[k][tx * 4];
      const double2 wb = *(const double2*)&Wd[k][tx * 4 + 2];
      const double xv[4] = {xa.x, xa.y, xb.x, xb.y};
      const double wv[4] = {wa.x, wa.y, wb.x, wb.y};
#pragma unroll
      for (int j = 0; j < 4; ++j)
#pragma unroll
        for (int i = 0; i < 4; ++i) acc[j][i] += xv[j] * wv[i];
    }
  }
  __syncthreads();
#pragma unroll
  for (int j = 0; j < 4; ++j) {
    unsigned int nib = 0u;
#pragma unroll
    for (int i = 0; i < 4; ++i) nib |= (acc[j][i] >= 1.0 ? 1u : 0u) << i;
    atomicOr(&spikes[ty * 4 + j][tx >> 3], nib << ((tx * 4) & 31));
  }
  __syncthreads();
  if (tid < 128) {
    const int r = tid >> 1;
    const int w = tid & 1;
    s1bits[(size_t)(b0 + r) * kFeatWords + (f0 >> 5) + w] = spikes[r][w];
  }
}

__global__ __launch_bounds__(256) void snn_fc2(const unsigned int* __restrict__ s1bits,
                                               const float* __restrict__ W2,
                                               float* __restrict__ out) {
  __shared__ double Wd[32][66];
  __shared__ unsigned int Sb[64];
  const int tid = threadIdx.x;
  const int tx = tid & 15;
  const int ty = tid >> 4;
  const int b0 = blockIdx.y * 64;
  const int o0 = blockIdx.x * 64;
  double acc[4][4];
#pragma unroll
  for (int j = 0; j < 4; ++j)
#pragma unroll
    for (int i = 0; i < 4; ++i) acc[j][i] = 0.0;
  const int rl = tid >> 2;
  const int kq = (tid & 3) * 8;
  int orow = o0 + rl;
  if (orow >= kOut) orow = kOut - 1;
  const float* wrow = W2 + (size_t)orow * kFeat + kq;
  for (int kc = 0; kc < kFeat; kc += 32) {
    const float4 wv0 = *(const float4*)(wrow + kc);
    const float4 wv1 = *(const float4*)(wrow + kc + 4);
    unsigned int sword = 0u;
    if (tid < 64) sword = s1bits[(size_t)(b0 + tid) * kFeatWords + (kc >> 5)];
    __syncthreads();
    Wd[kq + 0][rl] = (double)wv0.x; Wd[kq + 1][rl] = (double)wv0.y;
    Wd[kq + 2][rl] = (double)wv0.z; Wd[kq + 3][rl] = (double)wv0.w;
    Wd[kq + 4][rl] = (double)wv1.x; Wd[kq + 5][rl] = (double)wv1.y;
    Wd[kq + 6][rl] = (double)wv1.z; Wd[kq + 7][rl] = (double)wv1.w;
    if (tid < 64) Sb[tid] = sword;
    __syncthreads();
    const unsigned int rw0 = Sb[ty * 4 + 0];
    const unsigned int rw1 = Sb[ty * 4 + 1];
    const unsigned int rw2 = Sb[ty * 4 + 2];
    const unsigned int rw3 = Sb[ty * 4 + 3];
#pragma unroll
    for (int k = 0; k < 32; ++k) {
      const double2 wa = *(const double2*)&Wd[k][tx * 4];
      const double2 wb = *(const double2*)&Wd[k][tx * 4 + 2];
      const double wv[4] = {wa.x, wa.y, wb.x, wb.y};
      const double sv[4] = {(double)((rw0 >> k) & 1u), (double)((rw1 >> k) & 1u),
                            (double)((rw2 >> k) & 1u), (double)((rw3 >> k) & 1u)};
#pragma unroll
      for (int j = 0; j < 4; ++j)
#pragma unroll
        for (int i = 0; i < 4; ++i) acc[j][i] += sv[j] * wv[i];
    }
  }
#pragma unroll
  for (int j = 0; j < 4; ++j) {
    const int b = b0 + ty * 4 + j;
#pragma unroll
    for (int i = 0; i < 4; ++i) {
      const int o = o0 + tx * 4 + i;
      if (o < kOut) out[(size_t)b * kOut + o] = (acc[j][i] >= 1.0) ? 1.0f : 0.0f;
    }
  }
}

extern "C" void kernel_launch(void* const* d_in, const int* in_sizes, int n_in,
                              void* d_out, int out_size, void* d_ws, size_t ws_size,
                              hipStream_t stream) {
  const float* x = (const float*)d_in[0];
  const float* W1 = (const float*)d_in[1];
  const float* W2 = (const float*)d_in[2];
  float* out = (float*)d_out;

  char* p = (char*)d_ws;
  signed char* w1lF = (signed char*)p;   p += kW1F;
  signed char* w2lF = (signed char*)p;   p += kW2F;
  unsigned* s1b = (unsigned*)p;          p += kS1Bytes;
  unsigned* s1T = (unsigned*)p;          p += kS1Bytes;
  uint2* xb2 = (uint2*)p;                p += kXb2Bytes;
  unsigned* list1 = (unsigned*)p;        p += (size_t)kCap1 * 4;
  unsigned* list2 = (unsigned*)p;        p += (size_t)kCap2 * 4;
  unsigned* ctrs = (unsigned*)p;         p += 256;
  const size_t need = (size_t)(p - (char*)d_ws);  // ~85 MB

  if (ws_size >= need) {
    hipMemsetAsync(ctrs, 0, 32, stream);  // ctrs[0]=fc1 cnt, ctrs[4]=fc2 cnt
    conv_w1F<<<4802, 256, 0, stream>>>(W1, w1lF);
    conv_w2F<<<784, 256, 0, stream>>>(W2, w2lF);
    pack_x2<<<50176, 256, 0, stream>>>(x, xb2);
    fc1_v5<<<dim3(64, 98), 256, 0, stream>>>(xb2, w1lF, s1b, s1T, ctrs, list1);
    fc1_correct<<<1024, 256, 0, stream>>>(x, W1, ctrs, list1, s1b, s1T);
    fc2_v5<<<dim3(64, 8), 256, 0, stream>>>(s1T, w2lF, out, ctrs + 4, list2);
    fc2_correct<<<64, 256, 0, stream>>>(s1b, W2, ctrs + 4, list2, out);
  } else {
    unsigned* s1 = (unsigned*)d_ws;
    snn_fc1<<<dim3(98, 64), 256, 0, stream>>>(x, W1, s1);
    snn_fc2<<<dim3(8, 64), 256, 0, stream>>>(s1, W2, out);
  }
}

// Round 8
// 588.984 us; speedup vs baseline: 1.1113x; 1.0700x over previous
//
#include <hip/hip_runtime.h>

// SNN 2-layer forward: s2 = (( (x@W1.T >=1) @ W2.T) >= 1)
// B=4096, IN=3136, FEAT=6272, OUT=500; x and s1 binary {0,1}.
// Exact 3-limb i8-MFMA GEMM (w = d0*2^-7+d1*2^-14+d2*2^-21+r, |r|<=2^-22,
// i32 MFMA accumulation exact, f64 Horner exact) + worst-case-safe sparse
// fp64 correction of all dots with |v_hat-1| <= K*2^-22.
//
// Round-8: R7 was L2-return-BW bound (each wave privately loaded B ->
// 24 KB/tile/block incl. 2x waveM redundancy; ~7.4 GB total vs 56 B/cyc/CU
// L2 return ~= the measured 332 us). Fix: B deduped through LDS
// (global_load_lds once per block, 12 KB/tile), tile M=128 so acc=48 AGPR
// and ~108 regs/wave -> TWO 8-wave blocks/CU (launch_bounds(512,4)); the
// second block's waves fill the first's barrier drain. Per-CU: B 53 us of
// L2 return vs 110 us MFMA -> MFMA-bound. fc2: 2-wave blocks, grid
// (128,8)=1024 blocks (8/CU), register-dbuf barrier-free (B traffic tiny).

namespace {
constexpr int kB = 4096;
constexpr int kIn = 3136;        // 49 chunks of 64
constexpr int kFeat = 6272;      // 98 chunks of 64
constexpr int kFeatWords = 196;  // u32 per s1 row
constexpr int kOut = 500;
constexpr size_t kPlane1 = (size_t)kFeat * kIn;
constexpr size_t kW1F = 3 * kPlane1;                 // 59,006,976 (4802*12288)
constexpr size_t kW2F = (size_t)784 * 12288;         // 9,633,792
constexpr size_t kS1Bytes = (size_t)kB * kFeatWords * 4;  // 3,211,264 (x2)
constexpr size_t kXb2Bytes = (size_t)49 * kB * 8;    // 1,605,632
constexpr unsigned kCap1 = 2u << 20;
constexpr unsigned kCap2 = 1u << 16;
__device__ constexpr double kTau1 = 7.4769e-4;       // > 3136*2^-22
__device__ constexpr double kTau2 = 1.4955e-3;       // > 6272*2^-22
}  // namespace

typedef int v4i __attribute__((ext_vector_type(4)));
typedef int v16i __attribute__((ext_vector_type(16)));

__device__ __forceinline__ void gload_lds16(const void* g, void* l) {
  __builtin_amdgcn_global_load_lds((__attribute__((address_space(1))) void*)(g),
                                   (__attribute__((address_space(3))) void*)(l),
                                   16, 0, 0);
}

// 16 bits -> 16 i8 (byte i = bit i)
__device__ __forceinline__ v4i expand16(unsigned b) {
  unsigned u0 = (((b      ) & 0xFu) * 0x204081u) & 0x01010101u;
  unsigned u1 = (((b >> 4 ) & 0xFu) * 0x204081u) & 0x01010101u;
  unsigned u2 = (((b >> 8 ) & 0xFu) * 0x204081u) & 0x01010101u;
  unsigned u3 = (((b >> 12) & 0xFu) * 0x204081u) & 0x01010101u;
  return (v4i){(int)u0, (int)u1, (int)u2, (int)u3};
}

// exact 3-digit signed base-128 split; |w - sum| <= 2^-22
__device__ __forceinline__ void split3(float w, signed char* d) {
  float c = rintf(w * 128.f);
  d[0] = (signed char)(int)c;
  float r = fmaf(c, -7.8125e-03f, w);
  c = rintf(r * 16384.f);
  d[1] = (signed char)(int)c;
  r = fmaf(c, -6.103515625e-05f, r);
  c = rintf(r * 2097152.f);
  d[2] = (signed char)(int)c;
}

// ---------------------------------------------------------------------------
// W1 -> fragment-major limbs: slot(fb,kt,j,g) = 1KB of 64 feats x 16 k-bytes.
// ---------------------------------------------------------------------------
__global__ __launch_bounds__(256) void conv_w1F(const float* __restrict__ W,
                                                signed char* __restrict__ F) {
  const int bx = blockIdx.x;               // fb*49 + kt, < 4802
  const int fb = bx / 49;
  const int kt = bx % 49;
  const int f = threadIdx.x & 63;
  const int g = threadIdx.x >> 6;
  const float* src = W + (size_t)(fb * 64 + f) * kIn + kt * 64 + g * 16;
  union { signed char c[16]; int4 v; } o[3];
#pragma unroll
  for (int q = 0; q < 4; ++q) {
    const float4 w = *(const float4*)(src + q * 4);
    signed char d[4][3];
    split3(w.x, d[0]); split3(w.y, d[1]); split3(w.z, d[2]); split3(w.w, d[3]);
#pragma unroll
    for (int e = 0; e < 4; ++e)
#pragma unroll
      for (int j = 0; j < 3; ++j) o[j].c[q * 4 + e] = d[e][j];
  }
#pragma unroll
  for (int j = 0; j < 3; ++j)
    *(int4*)(F + ((size_t)bx * 3 + j) * 4096 + g * 1024 + f * 16) = o[j].v;
}

// W2 (padded to 512 rows) -> fragment-major limbs, slots (fb<8, kt<98, j, g)
__global__ __launch_bounds__(256) void conv_w2F(const float* __restrict__ W,
                                                signed char* __restrict__ F) {
  const int bx = blockIdx.x;               // fb*98 + kt, < 784
  const int fb = bx / 98;
  const int kt = bx % 98;
  const int f = threadIdx.x & 63;
  const int g = threadIdx.x >> 6;
  const int feat = fb * 64 + f;
  union { signed char c[16]; int4 v; } o[3];
#pragma unroll
  for (int q = 0; q < 4; ++q) {
    float4 w = {0.f, 0.f, 0.f, 0.f};
    if (feat < kOut)
      w = *(const float4*)(W + (size_t)feat * kFeat + kt * 64 + g * 16 + q * 4);
    signed char d[4][3];
    split3(w.x, d[0]); split3(w.y, d[1]); split3(w.z, d[2]); split3(w.w, d[3]);
#pragma unroll
    for (int e = 0; e < 4; ++e)
#pragma unroll
      for (int j = 0; j < 3; ++j) o[j].c[q * 4 + e] = d[e][j];
  }
#pragma unroll
  for (int j = 0; j < 3; ++j)
    *(int4*)(F + ((size_t)bx * 3 + j) * 4096 + g * 1024 + f * 16) = o[j].v;
}

// x -> transposed packed bits: xb2[kt*4096 + b]
__global__ __launch_bounds__(256) void pack_x2(const float* __restrict__ X,
                                               uint2* __restrict__ xb2) {
  const int wid = (blockIdx.x * 256 + threadIdx.x) >> 6;  // < 200,704
  const int lane = threadIdx.x & 63;
  const int b = wid / 49;
  const int g = wid % 49;
  const float v = X[(size_t)b * kIn + g * 64 + lane];
  const unsigned long long bal = __ballot(v != 0.f);
  if (lane == 0) xb2[(size_t)g * kB + b] = make_uint2((unsigned)bal, (unsigned)(bal >> 32));
}

// ---------------------------------------------------------------------------
// FC1 v6: tile M=128,N=64,BK=64; 512 thr = 8 waves (4 waveM x 2 waveN),
// wave tile 32x32, acc[3] (48 AGPR, ~108 regs). B deduped via
// global_load_lds dbuf (2x12KB), one barrier/iter; launch_bounds(512,4)
// -> 2 blocks/CU so the other block covers the barrier drain.
// Grid (32, 98): bM on x.
// ---------------------------------------------------------------------------
__global__ __launch_bounds__(512, 4) void fc1_v6(
    const uint2* __restrict__ xb2, const signed char* __restrict__ w1lF,
    unsigned* __restrict__ s1b, unsigned* __restrict__ s1T,
    unsigned* __restrict__ cnt, unsigned* __restrict__ list) {
  __shared__ __align__(16) signed char lds[24576];
  const int tid = threadIdx.x;
  const int lane = tid & 63;
  const int ln31 = lane & 31;
  const int half = lane >> 5;
  const int wv = tid >> 6;       // 0..7
  const int waveM = wv >> 1;     // 0..3
  const int waveN = wv & 1;      // 0..1
  const int bx = blockIdx.y;     // N-block (64 feats)
  const int bM = blockIdx.x * 128;

  // B staging: 12 slots/iter; wave wv stages slot wv, and wv+8 if wv<4
  const signed char* const gbase = w1lF + (size_t)bx * 49 * 12288;
  const bool has1 = (wv < 4);
  const unsigned sG0 = wv * 1024u + lane * 16u;
  const unsigned sL0 = wv * 1024u;
  const unsigned sG1 = (wv + 8) * 1024u + lane * 16u;
  const unsigned sL1 = (wv + 8) * 1024u;

  const uint2* const aptr = xb2 + bM + waveM * 32 + ln31;
  const unsigned bfeat = (waveN * 32 + ln31) * 16u;

  v16i acc[3] = {};
  uint2 aC, aN;
  aC = aptr[0];
  gload_lds16(gbase + sG0, lds + sL0);
  if (has1) gload_lds16(gbase + sG1, lds + sL1);

  for (int kt = 0; kt < 49; ++kt) {
    __syncthreads();  // drains stage(kt); prev compute done
    const int cb = (kt & 1) * 12288;
    if (kt < 48) {
      const int nb = ((kt + 1) & 1) * 12288;
      const size_t go = (size_t)(kt + 1) * 12288;
      gload_lds16(gbase + go + sG0, lds + nb + sL0);
      if (has1) gload_lds16(gbase + go + sG1, lds + nb + sL1);
      aN = aptr[(size_t)(kt + 1) * kB];
    }
#pragma unroll
    for (int kk = 0; kk < 2; ++kk) {
      const unsigned gsel = (kk * 2 + half) * 1024u;
      const v4i b0 = *(const v4i*)(lds + cb + 0 * 4096 + gsel + bfeat);
      const v4i b1 = *(const v4i*)(lds + cb + 1 * 4096 + gsel + bfeat);
      const v4i b2 = *(const v4i*)(lds + cb + 2 * 4096 + gsel + bfeat);
      const unsigned word = kk ? aC.y : aC.x;
      const v4i a = expand16((word >> (half * 16)) & 0xFFFFu);
      acc[0] = __builtin_amdgcn_mfma_i32_32x32x32_i8(a, b0, acc[0], 0, 0, 0);
      acc[1] = __builtin_amdgcn_mfma_i32_32x32x32_i8(a, b1, acc[1], 0, 0, 0);
      acc[2] = __builtin_amdgcn_mfma_i32_32x32x32_i8(a, b2, acc[2], 0, 0, 0);
    }
    aC = aN;
  }

  const double s7 = 0.0078125;
  const int word = bx * 2 + waveN;
  const int fcol = word * 32 + ln31;
#pragma unroll
  for (int t = 0; t < 16; ++t) {
    double v = (double)acc[2][t];
    v = v * s7 + (double)acc[1][t];
    v = v * s7 + (double)acc[0][t];
    v = v * s7;
    const unsigned long long bal = __ballot(v >= 1.0);
    const int mrow = bM + waveM * 32 + (t & 3) + 8 * (t >> 2);
    if (lane == 0) {
      s1b[(size_t)mrow * kFeatWords + word] = (unsigned)bal;
      s1T[(size_t)word * kB + mrow] = (unsigned)bal;
    }
    if (lane == 32) {
      s1b[(size_t)(mrow + 4) * kFeatWords + word] = (unsigned)(bal >> 32);
      s1T[(size_t)word * kB + mrow + 4] = (unsigned)(bal >> 32);
    }
    if (fabs(v - 1.0) <= kTau1) {
      const unsigned idx = atomicAdd(cnt, 1u);
      if (idx < kCap1) list[idx] = ((unsigned)(mrow + 4 * half) << 13) | (unsigned)fcol;
    }
  }
}

// exact fp64 recompute of flagged FC1 dots; fixes s1b AND s1T
__global__ __launch_bounds__(256) void fc1_correct(
    const float* __restrict__ x, const float* __restrict__ W1,
    const unsigned* __restrict__ cnt, const unsigned* __restrict__ list,
    unsigned* __restrict__ s1b, unsigned* __restrict__ s1T) {
  const unsigned n = min(cnt[0], kCap1);
  const int lane = threadIdx.x & 63;
  const int wid = (blockIdx.x * 256 + threadIdx.x) >> 6;
  const int nw = (gridDim.x * 256) >> 6;
  for (unsigned i = wid; i < n; i += nw) {
    const unsigned u = list[i];
    const int b = (int)(u >> 13);
    const int f = (int)(u & 8191u);
    double s = 0.0;
    for (int k = lane; k < kIn; k += 64)
      s = fma((double)x[(size_t)b * kIn + k], (double)W1[(size_t)f * kIn + k], s);
#pragma unroll
    for (int off = 32; off > 0; off >>= 1) s += __shfl_down(s, off);
    if (lane == 0) {
      const unsigned mask = 1u << (f & 31);
      unsigned* p1 = s1b + (size_t)b * kFeatWords + (f >> 5);
      unsigned* p2 = s1T + (size_t)(f >> 5) * kB + b;
      if (s >= 1.0) { atomicOr(p1, mask); atomicOr(p2, mask); }
      else          { atomicAnd(p1, ~mask); atomicAnd(p2, ~mask); }
    }
  }
}

// ---------------------------------------------------------------------------
// FC2 v6: barrier-free register-dbuf (R7 scheme), but 2-wave blocks (tile
// 32 rows x 64 outs) and grid (128, 8) = 1024 blocks -> 8 blocks/CU for
// latency interleave. A bits from s1T, B frags dwordx4 from L2.
// ---------------------------------------------------------------------------
__global__ __launch_bounds__(128, 4) void fc2_v6(
    const unsigned* __restrict__ s1T, const signed char* __restrict__ w2lF,
    float* __restrict__ out, unsigned* __restrict__ cnt,
    unsigned* __restrict__ list) {
  const int tid = threadIdx.x;
  const int lane = tid & 63;
  const int ln31 = lane & 31;
  const int half = lane >> 5;
  const int wvN = tid >> 6;    // 0..1 (waveN)
  const int bx = blockIdx.y;   // N-block (64 outs)
  const int bM = blockIdx.x * 32;

  const unsigned* const aptr = s1T + bM + ln31;
  const int fl = wvN * 32 + ln31;
  const signed char* const bbase =
      w2lF + (size_t)(bx * 98) * 12288 + half * 1024u + fl * 16u;

  v16i acc[3] = {};
  v4i b0[6], b1[6];
  uint2 a0, a1;

#define LOAD_TILE(nk, bf, ab)                                   \
  {                                                             \
    const signed char* bp = bbase + (size_t)(nk) * 12288;       \
    bf[0] = *(const v4i*)(bp);                                  \
    bf[1] = *(const v4i*)(bp + 2048);                           \
    bf[2] = *(const v4i*)(bp + 4096);                           \
    bf[3] = *(const v4i*)(bp + 6144);                           \
    bf[4] = *(const v4i*)(bp + 8192);                           \
    bf[5] = *(const v4i*)(bp + 10240);                          \
    (ab).x = aptr[(size_t)((nk) * 2) * kB];                     \
    (ab).y = aptr[(size_t)((nk) * 2 + 1) * kB];                 \
  }
#define COMPUTE_TILE(bf, ab)                                                    \
  {                                                                             \
    _Pragma("unroll")                                                           \
    for (int kk = 0; kk < 2; ++kk) {                                            \
      const unsigned word = kk ? (ab).y : (ab).x;                               \
      const v4i a = expand16((word >> (half * 16)) & 0xFFFFu);                  \
      acc[0] = __builtin_amdgcn_mfma_i32_32x32x32_i8(a, bf[kk], acc[0], 0,0,0); \
      acc[1] = __builtin_amdgcn_mfma_i32_32x32x32_i8(a, bf[2+kk], acc[1],0,0,0);\
      acc[2] = __builtin_amdgcn_mfma_i32_32x32x32_i8(a, bf[4+kk], acc[2],0,0,0);\
    }                                                                           \
  }

  LOAD_TILE(0, b0, a0);
  for (int kt = 0; kt + 2 <= 98; kt += 2) {
    LOAD_TILE(kt + 1, b1, a1);
    COMPUTE_TILE(b0, a0);
    const int nk2 = (kt + 2 < 98) ? kt + 2 : 97;  // last reload harmless
    LOAD_TILE(nk2, b0, a0);
    COMPUTE_TILE(b1, a1);
  }

  const double s7 = 0.0078125;
  const int o = bx * 64 + wvN * 32 + ln31;
#pragma unroll
  for (int t = 0; t < 16; ++t) {
    double v = (double)acc[2][t];
    v = v * s7 + (double)acc[1][t];
    v = v * s7 + (double)acc[0][t];
    v = v * s7;
    const int b = bM + (t & 3) + 8 * (t >> 2) + 4 * half;
    if (o < kOut) {
      out[(size_t)b * kOut + o] = (v >= 1.0) ? 1.0f : 0.0f;
      if (fabs(v - 1.0) <= kTau2) {
        const unsigned idx = atomicAdd(cnt, 1u);
        if (idx < kCap2) list[idx] = ((unsigned)b << 13) | (unsigned)o;
      }
    }
  }
#undef LOAD_TILE
#undef COMPUTE_TILE
}

// exact fp64 recompute of flagged FC2 dots (reads row-major s1b)
__global__ __launch_bounds__(256) void fc2_correct(
    const unsigned* __restrict__ s1b, const float* __restrict__ W2,
    const unsigned* __restrict__ cnt, const unsigned* __restrict__ list,
    float* __restrict__ out) {
  const unsigned n = min(cnt[0], kCap2);
  const int lane = threadIdx.x & 63;
  const int wid = (blockIdx.x * 256 + threadIdx.x) >> 6;
  const int nw = (gridDim.x * 256) >> 6;
  for (unsigned i = wid; i < n; i += nw) {
    const unsigned u = list[i];
    const int b = (int)(u >> 13);
    const int o = (int)(u & 8191u);
    double s = 0.0;
    for (int k = lane; k < kFeat; k += 64) {
      const unsigned w = s1b[(size_t)b * kFeatWords + (k >> 5)];
      if ((w >> (k & 31)) & 1u) s += (double)W2[(size_t)o * kFeat + k];
    }
#pragma unroll
    for (int off = 32; off > 0; off >>= 1) s += __shfl_down(s, off);
    if (lane == 0) out[(size_t)b * kOut + o] = (s >= 1.0) ? 1.0f : 0.0f;
  }
}

// ---------------------------------------------------------------------------
// fp64 fallback (round-1 validated) — only if ws too small.
// ---------------------------------------------------------------------------
__global__ __launch_bounds__(256) void snn_fc1(const float* __restrict__ x,
                                               const float* __restrict__ W1,
                                               unsigned int* __restrict__ s1bits) {
  __shared__ double Xd[32][66];
  __shared__ double Wd[32][66];
  __shared__ unsigned int spikes[64][2];
  const int tid = threadIdx.x;
  const int tx = tid & 15;
  const int ty = tid >> 4;
  const int b0 = blockIdx.y * 64;
  const int f0 = blockIdx.x * 64;
  if (tid < 128) spikes[tid >> 1][tid & 1] = 0u;
  double acc[4][4];
#pragma unroll
  for (int j = 0; j < 4; ++j)
#pragma unroll
    for (int i = 0; i < 4; ++i) acc[j][i] = 0.0;
  const int rl = tid >> 2;
  const int kq = (tid & 3) * 8;
  const float* xrow = x + (size_t)(b0 + rl) * kIn + kq;
  const float* wrow = W1 + (size_t)(f0 + rl) * kIn + kq;
  for (int kc = 0; kc < kIn; kc += 32) {
    const float4 xv0 = *(const float4*)(xrow + kc);
    const float4 xv1 = *(const float4*)(xrow + kc + 4);
    const float4 wv0 = *(const float4*)(wrow + kc);
    const float4 wv1 = *(const float4*)(wrow + kc + 4);
    __syncthreads();
    Xd[kq + 0][rl] = (double)xv0.x; Xd[kq + 1][rl] = (double)xv0.y;
    Xd[kq + 2][rl] = (double)xv0.z; Xd[kq + 3][rl] = (double)xv0.w;
    Xd[kq + 4][rl] = (double)xv1.x; Xd[kq + 5][rl] = (double)xv1.y;
    Xd[kq + 6][rl] = (double)xv1.z; Xd[kq + 7][rl] = (double)xv1.w;
    Wd[kq + 0][rl] = (double)wv0.x; Wd[kq + 1][rl] = (double)wv0.y;
    Wd[kq + 2][rl] = (double)wv0.z; Wd[kq + 3][rl] = (double)wv0.w;
    Wd[kq + 4][rl] = (double)wv1.x; Wd[kq + 5][rl] = (double)wv1.y;
    Wd[kq + 6][rl] = (double)wv1.z; Wd[kq + 7][rl] = (double)wv1.w;
    __syncthreads();
#pragma unroll
    for (int k = 0; k < 32; ++k) {
      const double2 xa = *(const double2*)&Xd[k][ty * 4];
      const double2 xb = *(const double2*)&Xd[k][ty * 4 + 2];
      const double2 wa = *(const double2*)&Wd[k][tx * 4];
      const double2 wb = *(const double2*)&Wd[k][tx * 4 + 2];
      const double xv[4] = {xa.x, xa.y, xb.x, xb.y};
      const double wv[4] = {wa.x, wa.y, wb.x, wb.y};
#pragma unroll
      for (int j = 0; j < 4; ++j)
#pragma unroll
        for (int i = 0; i < 4; ++i) acc[j][i] += xv[j] * wv[i];
    }
  }
  __syncthreads();
#pragma unroll
  for (int j = 0; j < 4; ++j) {
    unsigned int nib = 0u;
#pragma unroll
    for (int i = 0; i < 4; ++i) nib |= (acc[j][i] >= 1.0 ? 1u : 0u) << i;
    atomicOr(&spikes[ty * 4 + j][tx >> 3], nib << ((tx * 4) & 31));
  }
  __syncthreads();
  if (tid < 128) {
    const int r = tid >> 1;
    const int w = tid & 1;
    s1bits[(size_t)(b0 + r) * kFeatWords + (f0 >> 5) + w] = spikes[r][w];
  }
}

__global__ __launch_bounds__(256) void snn_fc2(const unsigned int* __restrict__ s1bits,
                                               const float* __restrict__ W2,
                                               float* __restrict__ out) {
  __shared__ double Wd[32][66];
  __shared__ unsigned int Sb[64];
  const int tid = threadIdx.x;
  const int tx = tid & 15;
  const int ty = tid >> 4;
  const int b0 = blockIdx.y * 64;
  const int o0 = blockIdx.x * 64;
  double acc[4][4];
#pragma unroll
  for (int j = 0; j < 4; ++j)
#pragma unroll
    for (int i = 0; i < 4; ++i) acc[j][i] = 0.0;
  const int rl = tid >> 2;
  const int kq = (tid & 3) * 8;
  int orow = o0 + rl;
  if (orow >= kOut) orow = kOut - 1;
  const float* wrow = W2 + (size_t)orow * kFeat + kq;
  for (int kc = 0; kc < kFeat; kc += 32) {
    const float4 wv0 = *(const float4*)(wrow + kc);
    const float4 wv1 = *(const float4*)(wrow + kc + 4);
    unsigned int sword = 0u;
    if (tid < 64) sword = s1bits[(size_t)(b0 + tid) * kFeatWords + (kc >> 5)];
    __syncthreads();
    Wd[kq + 0][rl] = (double)wv0.x; Wd[kq + 1][rl] = (double)wv0.y;
    Wd[kq + 2][rl] = (double)wv0.z; Wd[kq + 3][rl] = (double)wv0.w;
    Wd[kq + 4][rl] = (double)wv1.x; Wd[kq + 5][rl] = (double)wv1.y;
    Wd[kq + 6][rl] = (double)wv1.z; Wd[kq + 7][rl] = (double)wv1.w;
    if (tid < 64) Sb[tid] = sword;
    __syncthreads();
    const unsigned int rw0 = Sb[ty * 4 + 0];
    const unsigned int rw1 = Sb[ty * 4 + 1];
    const unsigned int rw2 = Sb[ty * 4 + 2];
    const unsigned int rw3 = Sb[ty * 4 + 3];
#pragma unroll
    for (int k = 0; k < 32; ++k) {
      const double2 wa = *(const double2*)&Wd[k][tx * 4];
      const double2 wb = *(const double2*)&Wd[k][tx * 4 + 2];
      const double wv[4] = {wa.x, wa.y, wb.x, wb.y};
      const double sv[4] = {(double)((rw0 >> k) & 1u), (double)((rw1 >> k) & 1u),
                            (double)((rw2 >> k) & 1u), (double)((rw3 >> k) & 1u)};
#pragma unroll
      for (int j = 0; j < 4; ++j)
#pragma unroll
        for (int i = 0; i < 4; ++i) acc[j][i] += sv[j] * wv[i];
    }
  }
#pragma unroll
  for (int j = 0; j < 4; ++j) {
    const int b = b0 + ty * 4 + j;
#pragma unroll
    for (int i = 0; i < 4; ++i) {
      const int o = o0 + tx * 4 + i;
      if (o < kOut) out[(size_t)b * kOut + o] = (acc[j][i] >= 1.0) ? 1.0f : 0.0f;
    }
  }
}

extern "C" void kernel_launch(void* const* d_in, const int* in_sizes, int n_in,
                              void* d_out, int out_size, void* d_ws, size_t ws_size,
                              hipStream_t stream) {
  const float* x = (const float*)d_in[0];
  const float* W1 = (const float*)d_in[1];
  const float* W2 = (const float*)d_in[2];
  float* out = (float*)d_out;

  char* p = (char*)d_ws;
  signed char* w1lF = (signed char*)p;   p += kW1F;
  signed char* w2lF = (signed char*)p;   p += kW2F;
  unsigned* s1b = (unsigned*)p;          p += kS1Bytes;
  unsigned* s1T = (unsigned*)p;          p += kS1Bytes;
  uint2* xb2 = (uint2*)p;                p += kXb2Bytes;
  unsigned* list1 = (unsigned*)p;        p += (size_t)kCap1 * 4;
  unsigned* list2 = (unsigned*)p;        p += (size_t)kCap2 * 4;
  unsigned* ctrs = (unsigned*)p;         p += 256;
  const size_t need = (size_t)(p - (char*)d_ws);  // ~85 MB

  if (ws_size >= need) {
    hipMemsetAsync(ctrs, 0, 32, stream);  // ctrs[0]=fc1 cnt, ctrs[4]=fc2 cnt
    conv_w1F<<<4802, 256, 0, stream>>>(W1, w1lF);
    conv_w2F<<<784, 256, 0, stream>>>(W2, w2lF);
    pack_x2<<<50176, 256, 0, stream>>>(x, xb2);
    fc1_v6<<<dim3(32, 98), 512, 0, stream>>>(xb2, w1lF, s1b, s1T, ctrs, list1);
    fc1_correct<<<1024, 256, 0, stream>>>(x, W1, ctrs, list1, s1b, s1T);
    fc2_v6<<<dim3(128, 8), 128, 0, stream>>>(s1T, w2lF, out, ctrs + 4, list2);
    fc2_correct<<<64, 256, 0, stream>>>(s1b, W2, ctrs + 4, list2, out);
  } else {
    unsigned* s1 = (unsigned*)d_ws;
    snn_fc1<<<dim3(98, 64), 256, 0, stream>>>(x, W1, s1);
    snn_fc2<<<dim3(8, 64), 256, 0, stream>>>(s1, W2, out);
  }
}